// Round 1
// 126.333 us; speedup vs baseline: 1.0043x; 1.0043x over previous
//
#include <hip/hip_runtime.h>
#include <hip/hip_bf16.h>
#include <float.h>

#define BATCH    32
#define NPRIORS  8732
#define NT       137            // tiles of 64 priors
#define NPAD     (NT * 64)      // 8768 (padded prior count)
#define NV4T     (NPAD / 4)     // 2192 float4 per class column
#define NCLASSES 81
#define NC1      80             // classes excluding background
#define TOPK     100
#define MAXDET   100
#define FLATC    (NC1 * TOPK)   // 8000
#define FV4      2000           // FLATC / 4
#define NCAND    512
#define NBIN     1024           // (bits>>18) - 3040 : exp + 5 mantissa bits
#define BINOFF   3040

// ---------------------------------------------------------------------------
// Kernel 1: softmax over classes + TILED transpose.
// scores_t layout: [B][NT][NC1][64]  (tile-major; each block writes one
// contiguous 20.5 KB region).
// ---------------------------------------------------------------------------
__global__ __launch_bounds__(256) void softmax_transpose_kernel(
    const float* __restrict__ logits, float* __restrict__ scores_t) {
  int b = blockIdx.x / NT;
  int tile = blockIdx.x - b * NT;
  int n0 = tile * 64;
  int rows = min(64, NPRIORS - n0);  // 64 or 28

  int t = threadIdx.x;
  int r = t >> 2;   // row within tile
  int q = t & 3;

  float* dstb = scores_t + (size_t)(b * NT + tile) * (NC1 * 64);

  if (r >= rows) {
    // pad slots must be +0.0 (bits==0 -> never histogrammed/selected)
#pragma unroll
    for (int k = 0; k < 20; ++k) {
      int c = q + (k << 2);
      if (c >= 1) dstb[(c - 1) * 64 + r] = 0.f;
    }
    if (q == 0) dstb[79 * 64 + r] = 0.f;
    return;
  }

  const float* rowp = logits + ((size_t)b * NPRIORS + n0 + r) * NCLASSES;

  float v[21];
#pragma unroll
  for (int k = 0; k < 20; ++k) v[k] = rowp[q + (k << 2)];
  v[20] = (q == 0) ? rowp[80] : -FLT_MAX;

  float m = -FLT_MAX;
#pragma unroll
  for (int k = 0; k < 20; ++k) m = fmaxf(m, v[k]);
  if (q == 0) m = fmaxf(m, v[20]);
  m = fmaxf(m, __shfl_xor(m, 1));
  m = fmaxf(m, __shfl_xor(m, 2));

  float s = 0.f;
#pragma unroll
  for (int k = 0; k < 20; ++k) {
    v[k] = expf(v[k] - m);
    s += v[k];
  }
  if (q == 0) {
    v[20] = expf(v[20] - m);
    s += v[20];
  }
  s += __shfl_xor(s, 1);
  s += __shfl_xor(s, 2);

#pragma unroll
  for (int k = 0; k < 20; ++k) {
    int c = q + (k << 2);
    if (c >= 1) dstb[(c - 1) * 64 + r] = v[k] / s;
  }
  if (q == 0) dstb[79 * 64 + r] = v[20] / s;
}

// ---------------------------------------------------------------------------
// Box decode (identical float expressions to the reference)
// ---------------------------------------------------------------------------
__device__ __forceinline__ float4 decode_box(float4 l, float4 p) {
  float cx = l.x * 0.1f * p.z + p.x;
  float cy = l.y * 0.1f * p.w + p.y;
  float w  = expf(l.z * 0.2f) * p.z;
  float h  = expf(l.w * 0.2f) * p.w;
  return make_float4(cx - w * 0.5f, cy - h * 0.5f, cx + w * 0.5f,
                     cy + h * 0.5f);
}

// ---------------------------------------------------------------------------
// Kernel 2: block-per-(batch,class) top-100 select, SINGLE global read.
// v2: conflict-free b128 histogram scan (replica pre-reduction staged in the
//     cand region), two-level (1024 -> 256 sub-bin) threshold refinement so
//     ncand ~<= 128, single-atomic wave compaction, and a register-resident
//     shfl bitonic sort in wave 0 (no LDS sort traffic, no sort barriers).
// ---------------------------------------------------------------------------
__global__ __launch_bounds__(256) void topk_select_kernel(
    const float* __restrict__ scores_t, unsigned long long* __restrict__ k_sel) {
  const int bc = blockIdx.x;
  const int b = bc / NC1;
  const int c = bc - b * NC1;
  const int t = threadIdx.x;
  const int lane = t & 63;
  const int w = t >> 6;

  __shared__ __align__(16) unsigned int hist[NBIN * 4];     // 16 KB (fine hist reuses first 4 KB)
  __shared__ __align__(16) unsigned long long cand[NCAND];  // 4 KB (scan stage reuses as uint[1024])
  __shared__ int s_cnt, s_cut, s_above, s_fcut, wtot[4];

  const float4* s4 = (const float4*)scores_t;
  const size_t base4 = (size_t)b * (NT * NC1 * 16) + (size_t)c * 16;

  // ---- single global read: 9 float4 = 36 floats into registers
  float va[36];
#pragma unroll
  for (int i = 0; i < 9; ++i) {
    int p = t + (i << 8);
    float4 v = make_float4(0.f, 0.f, 0.f, 0.f);
    if (p < NV4T) v = s4[base4 + (size_t)(p >> 4) * (NC1 * 16) + (p & 15)];
    va[4 * i + 0] = v.x; va[4 * i + 1] = v.y;
    va[4 * i + 2] = v.z; va[4 * i + 3] = v.w;
  }
#pragma unroll
  for (int j = 0; j < 36; ++j) asm volatile("" : "+v"(va[j]));  // pin live

  // ---- zero coarse hist with contiguous uint4 stores (conflict-free)
  uint4* h4 = (uint4*)hist;
  const uint4 z4 = make_uint4(0u, 0u, 0u, 0u);
#pragma unroll
  for (int i = 0; i < 4; ++i) h4[t + (i << 8)] = z4;
  if (t == 0) { s_cnt = 0; s_cut = 0; s_above = 0; s_fcut = 0; }
  __syncthreads();  // B0

  // ---- coarse histogram from registers (skip zeros: padding & exact-0)
#pragma unroll
  for (int j = 0; j < 36; ++j) {
    unsigned int bits = __float_as_uint(va[j]);
    if (bits != 0u) {
      int bin = (int)(bits >> 18) - BINOFF;
      bin = max(0, min(NBIN - 1, bin));
      atomicAdd(&hist[(bin << 2) | (lane & 3)], 1u);
    }
  }
  __syncthreads();  // B1

  // ---- replica pre-reduction: thread t reduces bins {t, t+256, t+512, t+768}
  //      h4[bin] is one contiguous 16B chunk per lane -> conflict-free b128.
  //      Summed counts staged into the cand region (uint[1024]).
  unsigned int* chist = (unsigned int*)cand;
  {
    unsigned int hs[4];
#pragma unroll
    for (int k = 0; k < 4; ++k) {
      uint4 hv = h4[t + (k << 8)];
      hs[k] = hv.x + hv.y + hv.z + hv.w;
    }
    // reads of h4 above complete before these writes are consumed (B2a)
#pragma unroll
    for (int k = 0; k < 4; ++k) chist[t + (k << 8)] = hs[k];
  }
  __syncthreads();  // B2a

  // ---- coarse scan: thread t owns contiguous bins 4t..4t+3 (one b128 read)
  int h[4];
  int ls = 0;
  {
    uint4 hv = ((const uint4*)cand)[t];
    h[0] = (int)hv.x; h[1] = (int)hv.y; h[2] = (int)hv.z; h[3] = (int)hv.w;
    ls = h[0] + h[1] + h[2] + h[3];
  }
  int s = ls;
#pragma unroll
  for (int off = 1; off < 64; off <<= 1) {
    int o = __shfl_down(s, off);
    if (lane + off < 64) s += o;
  }
  if (lane == 0) wtot[w] = s;
  __syncthreads();  // B2
  int upper = 0;
  for (int w2 = w + 1; w2 < 4; ++w2) upper += wtot[w2];
  int run = (s - ls) + upper;
  int cutbin = -1, abv = 0;
#pragma unroll
  for (int k = 3; k >= 0; --k) {
    if (run < TOPK && run + h[k] >= TOPK) { cutbin = (t << 2) + k; abv = run; }
    run += h[k];
  }
  if (cutbin >= 0) { s_cut = cutbin; s_above = abv; }
  // zero fine hist (first 1024 words of hist; coarse hist fully consumed)
  h4[t] = z4;
  __syncthreads();  // B3

  // ---- fine histogram: 256 sub-bins (bits>>10 & 0xFF) of the cut bin
  const int cutb = s_cut;
#pragma unroll
  for (int j = 0; j < 36; ++j) {
    unsigned int bits = __float_as_uint(va[j]);
    if (bits != 0u) {
      int bin = (int)(bits >> 18) - BINOFF;
      bin = max(0, min(NBIN - 1, bin));
      if (bin == cutb) {
        int sub = (int)((bits >> 10) & 0xFFu);
        atomicAdd(&hist[(sub << 2) | (lane & 3)], 1u);
      }
    }
  }
  // re-init cand (scan-stage use finished before B2; compact writes after B6)
  for (int p = t; p < NCAND; p += 256) cand[p] = ~0ull;
  __syncthreads();  // B4

  // ---- fine scan: thread t owns sub-bin t (one conflict-free b128 read)
  int fh;
  {
    uint4 fv = ((const uint4*)hist)[t];
    fh = (int)(fv.x + fv.y + fv.z + fv.w);
  }
  int fs = fh;
#pragma unroll
  for (int off = 1; off < 64; off <<= 1) {
    int o = __shfl_down(fs, off);
    if (lane + off < 64) fs += o;
  }
  if (lane == 0) wtot[w] = fs;
  __syncthreads();  // B5
  int fupper = 0;
  for (int w2 = w + 1; w2 < 4; ++w2) fupper += wtot[w2];
  int frun = (fs - fh) + fupper;
  int need = TOPK - s_above;  // in [1, 100]
  if (frun < need && frun + fh >= need) s_fcut = t;
  __syncthreads();  // B6

  const unsigned int cutK = ((unsigned int)cutb << 8) | (unsigned int)s_fcut;

  // ---- compaction: per-lane mask + one wave prefix-scan + one atomic/wave
  unsigned long long msk = 0ull;
  int cnt = 0;
#pragma unroll
  for (int j = 0; j < 36; ++j) {
    unsigned int bits = __float_as_uint(va[j]);
    if (bits != 0u) {
      int bin = (int)(bits >> 18) - BINOFF;
      bin = max(0, min(NBIN - 1, bin));
      unsigned int K = ((unsigned int)bin << 8) | ((bits >> 10) & 0xFFu);
      if (K >= cutK) { msk |= 1ull << j; ++cnt; }
    }
  }
  int inc = cnt;
#pragma unroll
  for (int off = 1; off < 64; off <<= 1) {
    int o = __shfl_up(inc, off);
    if (lane >= off) inc += o;
  }
  int wtotal = __shfl(inc, 63);
  int wbase = 0;
  if (lane == 63) wbase = atomicAdd(&s_cnt, wtotal);
  wbase = __shfl(wbase, 63);
  int pos = wbase + inc - cnt;
#pragma unroll
  for (int j = 0; j < 36; ++j) {
    if ((msk >> j) & 1ull) {
      if (pos < NCAND) {
        unsigned int bits = __float_as_uint(va[j]);
        int idx = ((t + ((j >> 2) << 8)) << 2) + (j & 3);
        cand[pos] = (((unsigned long long)(~bits)) << 32) | (unsigned int)idx;
      }
      ++pos;
    }
  }
  __syncthreads();  // B7

  const int ncand = min(s_cnt, NCAND);
  if (ncand <= 128) {
    // ---- register-resident bitonic sort of 128 keys in wave 0, zero LDS
    if (w == 0) {
      unsigned long long a  = cand[lane];        // position lane
      unsigned long long bb = cand[lane + 64];   // position lane+64
#pragma unroll
      for (int k2 = 2; k2 <= 128; k2 <<= 1) {
#pragma unroll
        for (int j = 64; j > 0; j >>= 1) {
          if (j >= k2) continue;
          if (j == 64) {
            // pair (lane, lane+64), ascending (k2==128)
            unsigned long long lo = a < bb ? a : bb;
            unsigned long long hi = a < bb ? bb : a;
            a = lo; bb = hi;
          } else {
            const bool lowl = (lane & j) == 0;
            const bool upA = ((lane) & k2) == 0;
            const bool upB = ((lane + 64) & k2) == 0;
            unsigned long long pa = __shfl_xor(a, j);
            unsigned long long pb = __shfl_xor(bb, j);
            a  = (upA == lowl) ? (a < pa ? a : pa) : (a > pa ? a : pa);
            bb = (upB == lowl) ? (bb < pb ? bb : pb) : (bb > pb ? bb : pb);
          }
        }
      }
      k_sel[(size_t)bc * TOPK + lane] = a;
      if (lane < TOPK - 64) k_sel[(size_t)bc * TOPK + 64 + lane] = bb;
    }
  } else {
    // ---- rare fallback: block-wide LDS bitonic (identical to prior version)
    int NS = 128;
    while (NS < ncand) NS <<= 1;
    for (int k2 = 2; k2 <= NS; k2 <<= 1) {
      for (int j = k2 >> 1; j > 0; j >>= 1) {
        if (j >= 128) {
          __syncthreads();
          for (int p = t; p < NS; p += 256) {
            int ixj = p ^ j;
            if (ixj > p) {
              unsigned long long a = cand[p], c2 = cand[ixj];
              bool up = ((p & k2) == 0);
              if (up ? (a > c2) : (a < c2)) { cand[p] = c2; cand[ixj] = a; }
            }
          }
          __syncthreads();
        } else {
          int base = w << 7;
          if (base < NS) {
#pragma unroll
            for (int half = 0; half < 2; ++half) {
              int p = base + lane + (half << 6);
              int ixj = p ^ j;
              if (ixj > p) {
                unsigned long long a = cand[p], c2 = cand[ixj];
                bool up = ((p & k2) == 0);
                if (up ? (a > c2) : (a < c2)) { cand[p] = c2; cand[ixj] = a; }
              }
            }
          }
        }
      }
    }
    __syncthreads();
    if (t < TOPK) k_sel[(size_t)bc * TOPK + t] = cand[t];
  }
}

// ---------------------------------------------------------------------------
// Kernel 3: block-per-(batch,class) NMS, 256 threads.
// Phase 1: threads t<100 stage decoded boxes/areas/scores to LDS.
// Phase 2: 4 waves build suppression-mask partials for j-quartiles
//          (box_j via uniform-address LDS broadcast reads).
// Phase 3: wave 0 ORs partials, runs serial greedy propagation, writes out.
// IoU / decode arithmetic identical to previous passing version.
// ---------------------------------------------------------------------------
__global__ __launch_bounds__(256) void nms_kernel(
    const unsigned long long* __restrict__ k_sel,
    const float* __restrict__ loc, const float* __restrict__ priors,
    float* __restrict__ s_k, float* __restrict__ b_k) {
  const int t = threadIdx.x;
  const int lane = t & 63;
  const int w = t >> 6;
  const int bc = blockIdx.x;
  const int b = bc / NC1;

  __shared__ __align__(16) float4 lbox[TOPK];
  __shared__ float larea[TOPK];
  __shared__ float lscore[TOPK];
  __shared__ unsigned long long pm[4][64][3];  // per-wave partial masks
  __shared__ unsigned long long keepw[2];

  // ---- phase 1: stage rows 0..99
  if (t < TOPK) {
    unsigned long long key = k_sel[(size_t)bc * TOPK + t];
    float sv = __uint_as_float(~(unsigned int)(key >> 32));
    int idx = (int)(key & 0xFFFFFFFFull);
    if ((unsigned)idx >= NPRIORS) { idx = 0; sv = 0.f; }
    float4 bx = decode_box(((const float4*)loc)[(size_t)b * NPRIORS + idx],
                           ((const float4*)priors)[idx]);
    lbox[t] = bx;
    larea[t] = fmaxf(bx.z - bx.x, 0.f) * fmaxf(bx.w - bx.y, 0.f);
    lscore[t] = sv;
  }
  __syncthreads();

  // per-lane row data (rows A=lane, B=lane+64)
  const bool hasb = (lane + 64) < TOPK;
  float4 ba = lbox[lane];
  float aa = larea[lane];
  float4 bb2 = lbox[hasb ? (lane + 64) : 0];
  float ab = larea[hasb ? (lane + 64) : 0];

  // ---- phase 2: partial masks for j in this wave's quartile
  unsigned long long ra0 = 0, ra1 = 0, rb1 = 0;
  int jlo = max(1, w * 25);
  int jhi = min(TOPK, w * 25 + 25);
  for (int j = jlo; j < jhi; ++j) {
    float4 bj = lbox[j];      // uniform address -> broadcast
    float aj = larea[j];
    if (lane < j) {
      float iw = fmaxf(fminf(ba.z, bj.z) - fmaxf(ba.x, bj.x), 0.f);
      float ih = fmaxf(fminf(ba.w, bj.w) - fmaxf(ba.y, bj.y), 0.f);
      float inter = iw * ih;
      float iou = inter / (aa + aj - inter + 1e-9f);
      if (iou > 0.45f) {
        if (j < 64) ra0 |= 1ull << j; else ra1 |= 1ull << (j - 64);
      }
    }
    if (hasb && (lane + 64) < j) {   // j is then >= 65 -> upper half
      float iw = fmaxf(fminf(bb2.z, bj.z) - fmaxf(bb2.x, bj.x), 0.f);
      float ih = fmaxf(fminf(bb2.w, bj.w) - fmaxf(bb2.y, bj.y), 0.f);
      float inter = iw * ih;
      float iou = inter / (ab + aj - inter + 1e-9f);
      if (iou > 0.45f) rb1 |= 1ull << (j - 64);
    }
  }
  pm[w][lane][0] = ra0;
  pm[w][lane][1] = ra1;
  pm[w][lane][2] = rb1;
  __syncthreads();

  // ---- phase 3: wave 0 combines + propagates
  if (w == 0) {
    unsigned long long fa0 = pm[0][lane][0] | pm[1][lane][0] |
                             pm[2][lane][0] | pm[3][lane][0];
    unsigned long long fa1 = pm[0][lane][1] | pm[1][lane][1] |
                             pm[2][lane][1] | pm[3][lane][1];
    unsigned long long fb1 = pm[0][lane][2] | pm[1][lane][2] |
                             pm[2][lane][2] | pm[3][lane][2];

    float sva = lscore[lane];
    float svb = hasb ? lscore[lane + 64] : 0.f;
    unsigned long long keep0 = __ballot(sva > 0.01f);
    unsigned long long keep1 = __ballot(hasb && (svb > 0.01f));
    for (int i = 0; i < TOPK; ++i) {
      bool il = i < 64;
      bool kb = il ? ((keep0 >> i) & 1ull) : ((keep1 >> (i - 64)) & 1ull);
      unsigned long long m0 = __shfl(il ? fa0 : 0ull, i & 63);
      unsigned long long m1 = __shfl(il ? fa1 : fb1, i & 63);
      if (kb) { keep0 &= ~m0; keep1 &= ~m1; }
    }
    if (lane == 0) { keepw[0] = keep0; keepw[1] = keep1; }
  }
  __syncthreads();

  // ---- outputs (threads 0..99)
  if (t < TOPK) {
    bool kp = (t < 64) ? ((keepw[0] >> t) & 1ull)
                       : ((keepw[1] >> (t - 64)) & 1ull);
    s_k[(size_t)bc * TOPK + t] = kp ? lscore[t] : 0.f;
    ((float4*)(b_k + (size_t)bc * TOPK * 4))[t] = lbox[t];
  }
}

// ---------------------------------------------------------------------------
// Kernel 4: per-image exact top-100 over 8000 candidates
// out layout: boxes[32][100][4] | scores[32][100] | labels[32][100] (as f32)
// ---------------------------------------------------------------------------
__global__ __launch_bounds__(256) void final_topk_kernel(
    const float* __restrict__ s_k, const float* __restrict__ b_k,
    float* __restrict__ out) {
  const int b = blockIdx.x;
  const int t = threadIdx.x;
  const int lane = t & 63;
  const int w = t >> 6;

  __shared__ __align__(16) unsigned int hist[NBIN * 4];
  __shared__ __align__(16) unsigned long long cand[NCAND];
  __shared__ int s_cnt, s_cut, wtot[4];

  const float4* src4 = (const float4*)(s_k + (size_t)b * FLATC);

#pragma unroll
  for (int i = 0; i < 16; ++i) hist[t + (i << 8)] = 0u;
  if (t == 0) { s_cnt = 0; s_cut = 0; }
  __syncthreads();

#pragma unroll
  for (int i = 0; i < 8; ++i) {
    int p = t + (i << 8);
    if (p < FV4) {
      float4 v = src4[p];
      float vv[4] = {v.x, v.y, v.z, v.w};
#pragma unroll
      for (int c = 0; c < 4; ++c) {
        unsigned int bits = __float_as_uint(vv[c]);
        if (bits != 0u) {
          int bin = (int)(bits >> 18) - BINOFF;
          bin = max(0, min(NBIN - 1, bin));
          atomicAdd(&hist[(bin << 2) | (lane & 3)], 1u);
        }
      }
    }
  }
  __syncthreads();

  int h[4];
  int ls = 0;
#pragma unroll
  for (int k = 0; k < 4; ++k) {
    int bn = (t << 2) + k;
    h[k] = (int)(hist[(bn << 2) + 0] + hist[(bn << 2) + 1] +
                 hist[(bn << 2) + 2] + hist[(bn << 2) + 3]);
    ls += h[k];
  }
  for (int p = t; p < NCAND; p += 256) cand[p] = ~0ull;
  int s = ls;
#pragma unroll
  for (int off = 1; off < 64; off <<= 1) {
    int o = __shfl_down(s, off);
    if (lane + off < 64) s += o;
  }
  if (lane == 0) wtot[w] = s;
  __syncthreads();
  int upper = 0;
  for (int w2 = w + 1; w2 < 4; ++w2) upper += wtot[w2];
  int run = (s - ls) + upper;
  int cutbin = -1;
#pragma unroll
  for (int k = 3; k >= 0; --k) {
    if (run < TOPK && run + h[k] >= TOPK) cutbin = (t << 2) + k;
    run += h[k];
  }
  if (cutbin >= 0) s_cut = cutbin;
  __syncthreads();

  unsigned int cutbits = (unsigned int)(s_cut + BINOFF) << 18;

#pragma unroll
  for (int i = 0; i < 8; ++i) {
    int p = t + (i << 8);
    bool inb = (p < FV4);
    float4 v = make_float4(0.f, 0.f, 0.f, 0.f);
    if (inb) v = src4[p];
    float vv[4] = {v.x, v.y, v.z, v.w};
#pragma unroll
    for (int c = 0; c < 4; ++c) {
      unsigned int bits = __float_as_uint(vv[c]);
      bool pred = inb && (bits >= cutbits);
      unsigned long long m = __ballot(pred);
      if (m) {
        int base = 0;
        if (lane == 0) base = atomicAdd(&s_cnt, (int)__popcll(m));
        base = __shfl(base, 0);
        if (pred) {
          int pos = base + (int)__popcll(m & ((1ull << lane) - 1ull));
          if (pos < NCAND)
            cand[pos] = (((unsigned long long)(~bits)) << 32) |
                        (unsigned int)((p << 2) + c);
        }
      }
    }
  }
  __syncthreads();

  int ncand = min(s_cnt, NCAND);
  int NS = 128;
  while (NS < ncand) NS <<= 1;
  for (int k2 = 2; k2 <= NS; k2 <<= 1) {
    for (int j = k2 >> 1; j > 0; j >>= 1) {
      if (j >= 128) {
        __syncthreads();
        for (int p = t; p < NS; p += 256) {
          int ixj = p ^ j;
          if (ixj > p) {
            unsigned long long a = cand[p], c2 = cand[ixj];
            bool up = ((p & k2) == 0);
            if (up ? (a > c2) : (a < c2)) { cand[p] = c2; cand[ixj] = a; }
          }
        }
        __syncthreads();
      } else {
        int base = w << 7;
        if (base < NS) {
#pragma unroll
          for (int half = 0; half < 2; ++half) {
            int p = base + lane + (half << 6);
            int ixj = p ^ j;
            if (ixj > p) {
              unsigned long long a = cand[p], c2 = cand[ixj];
              bool up = ((p & k2) == 0);
              if (up ? (a > c2) : (a < c2)) { cand[p] = c2; cand[ixj] = a; }
            }
          }
        }
      }
    }
  }
  __syncthreads();

  if (t < MAXDET) {
    unsigned long long key = cand[t];
    unsigned int vb = ~(unsigned int)(key >> 32);
    float sv = __uint_as_float(vb);
    int f = (int)(key & 0xFFFFFFFFull);
    if ((unsigned)f >= FLATC) { f = 0; sv = 0.f; }
    float4 bb = *(const float4*)(b_k + ((size_t)b * FLATC + f) * 4);
    ((float4*)out)[b * MAXDET + t] = bb;
    out[BATCH * MAXDET * 4 + b * MAXDET + t] = sv;
    int cls = f / TOPK + 1;
    out[BATCH * MAXDET * 5 + b * MAXDET + t] = (float)cls;
  }
}

// ---------------------------------------------------------------------------
extern "C" void kernel_launch(void* const* d_in, const int* in_sizes, int n_in,
                              void* d_out, int out_size, void* d_ws,
                              size_t ws_size, hipStream_t stream) {
  const float* cls_logits = (const float*)d_in[0];
  const float* bbox_pred  = (const float*)d_in[1];
  const float* priors     = (const float*)d_in[2];
  float* out = (float*)d_out;

  float* scores_t = (float*)d_ws;                                  // [B][NT][80][64]
  float* s_k = scores_t + (size_t)BATCH * NT * NC1 * 64;           // [2560][100]
  float* b_k = s_k + (size_t)BATCH * NC1 * TOPK;                   // [2560][100][4]
  unsigned long long* k_sel =
      (unsigned long long*)(b_k + (size_t)BATCH * NC1 * TOPK * 4); // [2560][100]

  softmax_transpose_kernel<<<BATCH * NT, 256, 0, stream>>>(cls_logits,
                                                           scores_t);
  topk_select_kernel<<<BATCH * NC1, 256, 0, stream>>>(scores_t, k_sel);
  nms_kernel<<<BATCH * NC1, 256, 0, stream>>>(k_sel, bbox_pred, priors,
                                              s_k, b_k);
  final_topk_kernel<<<BATCH, 256, 0, stream>>>(s_k, b_k, out);
}

// Round 2
// 106.470 us; speedup vs baseline: 1.1917x; 1.1866x over previous
//
#include <hip/hip_runtime.h>
#include <hip/hip_bf16.h>
#include <float.h>

#define BATCH    32
#define NPRIORS  8732
#define NT       137            // tiles of 64 priors
#define NPAD     (NT * 64)      // 8768 (padded prior count)
#define NV4T     (NPAD / 4)     // 2192 float4 per class column
#define NCLASSES 81
#define NC1      80             // classes excluding background
#define TOPK     100
#define MAXDET   100
#define FLATC    (NC1 * TOPK)   // 8000
#define FV4      2000           // FLATC / 4
#define NCAND    512
#define NBIN     1024           // (bits>>18) - 3040 : exp + 5 mantissa bits
#define BINOFF   3040

// ---------------------------------------------------------------------------
// Kernel 1: softmax over classes + TILED transpose.
// scores_t layout: [B][NT][NC1][64]  (tile-major; each block writes one
// contiguous 20.5 KB region).
// ---------------------------------------------------------------------------
__global__ __launch_bounds__(256) void softmax_transpose_kernel(
    const float* __restrict__ logits, float* __restrict__ scores_t) {
  int b = blockIdx.x / NT;
  int tile = blockIdx.x - b * NT;
  int n0 = tile * 64;
  int rows = min(64, NPRIORS - n0);  // 64 or 28

  int t = threadIdx.x;
  int r = t >> 2;   // row within tile
  int q = t & 3;

  float* dstb = scores_t + (size_t)(b * NT + tile) * (NC1 * 64);

  if (r >= rows) {
    // pad slots must be +0.0 (bits==0 -> never histogrammed/selected)
#pragma unroll
    for (int k = 0; k < 20; ++k) {
      int c = q + (k << 2);
      if (c >= 1) dstb[(c - 1) * 64 + r] = 0.f;
    }
    if (q == 0) dstb[79 * 64 + r] = 0.f;
    return;
  }

  const float* rowp = logits + ((size_t)b * NPRIORS + n0 + r) * NCLASSES;

  float v[21];
#pragma unroll
  for (int k = 0; k < 20; ++k) v[k] = rowp[q + (k << 2)];
  v[20] = (q == 0) ? rowp[80] : -FLT_MAX;

  float m = -FLT_MAX;
#pragma unroll
  for (int k = 0; k < 20; ++k) m = fmaxf(m, v[k]);
  if (q == 0) m = fmaxf(m, v[20]);
  m = fmaxf(m, __shfl_xor(m, 1));
  m = fmaxf(m, __shfl_xor(m, 2));

  float s = 0.f;
#pragma unroll
  for (int k = 0; k < 20; ++k) {
    v[k] = expf(v[k] - m);
    s += v[k];
  }
  if (q == 0) {
    v[20] = expf(v[20] - m);
    s += v[20];
  }
  s += __shfl_xor(s, 1);
  s += __shfl_xor(s, 2);

#pragma unroll
  for (int k = 0; k < 20; ++k) {
    int c = q + (k << 2);
    if (c >= 1) dstb[(c - 1) * 64 + r] = v[k] / s;
  }
  if (q == 0) dstb[79 * 64 + r] = v[20] / s;
}

// ---------------------------------------------------------------------------
// Box decode (identical float expressions to the reference)
// ---------------------------------------------------------------------------
__device__ __forceinline__ float4 decode_box(float4 l, float4 p) {
  float cx = l.x * 0.1f * p.z + p.x;
  float cy = l.y * 0.1f * p.w + p.y;
  float w  = expf(l.z * 0.2f) * p.z;
  float h  = expf(l.w * 0.2f) * p.w;
  return make_float4(cx - w * 0.5f, cy - h * 0.5f, cx + w * 0.5f,
                     cy + h * 0.5f);
}

// ---------------------------------------------------------------------------
// Bitonic compare-exchange helper for the 256-slot all-thread sort.
// ---------------------------------------------------------------------------
__device__ __forceinline__ unsigned long long cex(unsigned long long key,
                                                  unsigned long long p,
                                                  bool up, bool low) {
  return (up == low) ? (key < p ? key : p) : (key > p ? key : p);
}

// ---------------------------------------------------------------------------
// Kernel 2: block-per-(batch,class) top-100 select, SINGLE global read.
// v3: latency-focused. LDS shrunk to 12.3 KB (2-replica hist) -> 8 blocks/CU
//     (hardware wave cap, 100% static occupancy). Coarse cut only (cut-bin
//     population at rank-100 is ~3-5, so ncand ~<= 130). Single-pass mask
//     compaction (1 atomic/wave). Sort: 256 keys, one per thread, bitonic
//     with 33 in-wave shfl stages + 3 LDS-exchange stages -- all waves
//     active, no serial wave-0 tail. 512-slot LDS bitonic fallback.
// ---------------------------------------------------------------------------
__global__ __launch_bounds__(256, 8) void topk_select_kernel(
    const float* __restrict__ scores_t, unsigned long long* __restrict__ k_sel) {
  const int bc = blockIdx.x;
  const int b = bc / NC1;
  const int c = bc - b * NC1;
  const int t = threadIdx.x;
  const int lane = t & 63;
  const int w = t >> 6;

  __shared__ __align__(16) unsigned int hist[NBIN * 2];     // 8 KB, 2 replicas
  __shared__ __align__(16) unsigned long long cand[NCAND];  // 4 KB
  __shared__ int s_cnt, s_cut, wtot[4];

  const float4* s4 = (const float4*)scores_t;
  const size_t base4 = (size_t)b * (NT * NC1 * 16) + (size_t)c * 16;

  // ---- single global read: 9 float4 = 36 floats into registers
  float va[36];
#pragma unroll
  for (int i = 0; i < 9; ++i) {
    int p = t + (i << 8);
    float4 v = make_float4(0.f, 0.f, 0.f, 0.f);
    if (p < NV4T) v = s4[base4 + (size_t)(p >> 4) * (NC1 * 16) + (p & 15)];
    va[4 * i + 0] = v.x; va[4 * i + 1] = v.y;
    va[4 * i + 2] = v.z; va[4 * i + 3] = v.w;
  }
#pragma unroll
  for (int j = 0; j < 36; ++j) asm volatile("" : "+v"(va[j]));  // pin live

  // ---- zero hist (2048 words) + init cand + counters
  uint4* h4 = (uint4*)hist;
  const uint4 z4 = make_uint4(0u, 0u, 0u, 0u);
  h4[t] = z4;
  h4[t + 256] = z4;
  cand[t] = ~0ull;
  cand[t + 256] = ~0ull;
  if (t == 0) { s_cnt = 0; s_cut = 0; }
  __syncthreads();  // B0

  // ---- coarse histogram from registers (skip zeros: padding & exact-0)
#pragma unroll
  for (int j = 0; j < 36; ++j) {
    unsigned int bits = __float_as_uint(va[j]);
    if (bits != 0u) {
      int bin = (int)(bits >> 18) - BINOFF;
      bin = max(0, min(NBIN - 1, bin));
      atomicAdd(&hist[(bin << 1) | (lane & 1)], 1u);
    }
  }
  __syncthreads();  // B1

  // ---- scan: thread t owns bins 4t..4t+3 (words 8t..8t+7, two b128 reads)
  int h[4];
  int ls;
  {
    uint4 a = h4[2 * t];
    uint4 b2 = h4[2 * t + 1];
    h[0] = (int)(a.x + a.y);
    h[1] = (int)(a.z + a.w);
    h[2] = (int)(b2.x + b2.y);
    h[3] = (int)(b2.z + b2.w);
    ls = h[0] + h[1] + h[2] + h[3];
  }
  int s = ls;
#pragma unroll
  for (int off = 1; off < 64; off <<= 1) {
    int o = __shfl_down(s, off);
    if (lane + off < 64) s += o;
  }
  if (lane == 0) wtot[w] = s;
  __syncthreads();  // B2
  int upper = 0;
  for (int w2 = w + 1; w2 < 4; ++w2) upper += wtot[w2];
  int run = (s - ls) + upper;
  int cutbin = -1;
#pragma unroll
  for (int k = 3; k >= 0; --k) {
    if (run < TOPK && run + h[k] >= TOPK) cutbin = (t << 2) + k;
    run += h[k];
  }
  if (cutbin >= 0) s_cut = cutbin;
  __syncthreads();  // B3

  const unsigned int cutbits = (unsigned int)(s_cut + BINOFF) << 18;

  // ---- compaction: per-lane mask + one wave prefix-scan + one atomic/wave
  unsigned long long msk = 0ull;
  int cnt = 0;
#pragma unroll
  for (int j = 0; j < 36; ++j) {
    unsigned int bits = __float_as_uint(va[j]);
    if (bits >= cutbits) { msk |= 1ull << j; ++cnt; }  // cutbits>0 excludes 0
  }
  int inc = cnt;
#pragma unroll
  for (int off = 1; off < 64; off <<= 1) {
    int o = __shfl_up(inc, off);
    if (lane >= off) inc += o;
  }
  int wtotal = __shfl(inc, 63);
  int wbase = 0;
  if (lane == 63) wbase = atomicAdd(&s_cnt, wtotal);
  wbase = __shfl(wbase, 63);
  int pos = wbase + inc - cnt;
#pragma unroll
  for (int j = 0; j < 36; ++j) {
    if ((msk >> j) & 1ull) {
      if (pos < NCAND) {
        unsigned int bits = __float_as_uint(va[j]);
        int idx = ((t + ((j >> 2) << 8)) << 2) + (j & 3);
        cand[pos] = (((unsigned long long)(~bits)) << 32) | (unsigned int)idx;
      }
      ++pos;
    }
  }
  __syncthreads();  // B4

  const int ncand = s_cnt;
  if (ncand <= 256) {
    // ---- 256-key bitonic, one key per thread; shfl in-wave, LDS for j>=64
    unsigned long long key = cand[t];
#pragma unroll
    for (int k2 = 2; k2 <= 256; k2 <<= 1) {
#pragma unroll
      for (int j = 128; j > 0; j >>= 1) {
        if (j >= k2) continue;
        const bool up = ((t & k2) == 0);
        if (j >= 64) {
          cand[t] = key;
          __syncthreads();
          unsigned long long p = cand[t ^ j];
          key = cex(key, p, up, (t & j) == 0);
          __syncthreads();
        } else {
          unsigned long long p = __shfl_xor(key, j);
          key = cex(key, p, up, (lane & j) == 0);
        }
      }
    }
    if (t < TOPK) k_sel[(size_t)bc * TOPK + t] = key;
  } else {
    // ---- rare fallback: block-wide LDS bitonic over 512
    int NS = 512;
    for (int k2 = 2; k2 <= NS; k2 <<= 1) {
      for (int j = k2 >> 1; j > 0; j >>= 1) {
        if (j >= 128) {
          __syncthreads();
          for (int p = t; p < NS; p += 256) {
            int ixj = p ^ j;
            if (ixj > p) {
              unsigned long long a = cand[p], c2 = cand[ixj];
              bool up = ((p & k2) == 0);
              if (up ? (a > c2) : (a < c2)) { cand[p] = c2; cand[ixj] = a; }
            }
          }
          __syncthreads();
        } else {
          int base = w << 7;
          if (base < NS) {
#pragma unroll
            for (int half = 0; half < 2; ++half) {
              int p = base + lane + (half << 6);
              int ixj = p ^ j;
              if (ixj > p) {
                unsigned long long a = cand[p], c2 = cand[ixj];
                bool up = ((p & k2) == 0);
                if (up ? (a > c2) : (a < c2)) { cand[p] = c2; cand[ixj] = a; }
              }
            }
          }
        }
      }
    }
    __syncthreads();
    if (t < TOPK) k_sel[(size_t)bc * TOPK + t] = cand[t];
  }
}

// ---------------------------------------------------------------------------
// Kernel 3: block-per-(batch,class) NMS, 256 threads.
// ---------------------------------------------------------------------------
__global__ __launch_bounds__(256) void nms_kernel(
    const unsigned long long* __restrict__ k_sel,
    const float* __restrict__ loc, const float* __restrict__ priors,
    float* __restrict__ s_k, float* __restrict__ b_k) {
  const int t = threadIdx.x;
  const int lane = t & 63;
  const int w = t >> 6;
  const int bc = blockIdx.x;
  const int b = bc / NC1;

  __shared__ __align__(16) float4 lbox[TOPK];
  __shared__ float larea[TOPK];
  __shared__ float lscore[TOPK];
  __shared__ unsigned long long pm[4][64][3];  // per-wave partial masks
  __shared__ unsigned long long keepw[2];

  // ---- phase 1: stage rows 0..99
  if (t < TOPK) {
    unsigned long long key = k_sel[(size_t)bc * TOPK + t];
    float sv = __uint_as_float(~(unsigned int)(key >> 32));
    int idx = (int)(key & 0xFFFFFFFFull);
    if ((unsigned)idx >= NPRIORS) { idx = 0; sv = 0.f; }
    float4 bx = decode_box(((const float4*)loc)[(size_t)b * NPRIORS + idx],
                           ((const float4*)priors)[idx]);
    lbox[t] = bx;
    larea[t] = fmaxf(bx.z - bx.x, 0.f) * fmaxf(bx.w - bx.y, 0.f);
    lscore[t] = sv;
  }
  __syncthreads();

  // per-lane row data (rows A=lane, B=lane+64)
  const bool hasb = (lane + 64) < TOPK;
  float4 ba = lbox[lane];
  float aa = larea[lane];
  float4 bb2 = lbox[hasb ? (lane + 64) : 0];
  float ab = larea[hasb ? (lane + 64) : 0];

  // ---- phase 2: partial masks for j in this wave's quartile
  unsigned long long ra0 = 0, ra1 = 0, rb1 = 0;
  int jlo = max(1, w * 25);
  int jhi = min(TOPK, w * 25 + 25);
  for (int j = jlo; j < jhi; ++j) {
    float4 bj = lbox[j];      // uniform address -> broadcast
    float aj = larea[j];
    if (lane < j) {
      float iw = fmaxf(fminf(ba.z, bj.z) - fmaxf(ba.x, bj.x), 0.f);
      float ih = fmaxf(fminf(ba.w, bj.w) - fmaxf(ba.y, bj.y), 0.f);
      float inter = iw * ih;
      float iou = inter / (aa + aj - inter + 1e-9f);
      if (iou > 0.45f) {
        if (j < 64) ra0 |= 1ull << j; else ra1 |= 1ull << (j - 64);
      }
    }
    if (hasb && (lane + 64) < j) {   // j is then >= 65 -> upper half
      float iw = fmaxf(fminf(bb2.z, bj.z) - fmaxf(bb2.x, bj.x), 0.f);
      float ih = fmaxf(fminf(bb2.w, bj.w) - fmaxf(bb2.y, bj.y), 0.f);
      float inter = iw * ih;
      float iou = inter / (ab + aj - inter + 1e-9f);
      if (iou > 0.45f) rb1 |= 1ull << (j - 64);
    }
  }
  pm[w][lane][0] = ra0;
  pm[w][lane][1] = ra1;
  pm[w][lane][2] = rb1;
  __syncthreads();

  // ---- phase 3: wave 0 combines + propagates
  if (w == 0) {
    unsigned long long fa0 = pm[0][lane][0] | pm[1][lane][0] |
                             pm[2][lane][0] | pm[3][lane][0];
    unsigned long long fa1 = pm[0][lane][1] | pm[1][lane][1] |
                             pm[2][lane][1] | pm[3][lane][1];
    unsigned long long fb1 = pm[0][lane][2] | pm[1][lane][2] |
                             pm[2][lane][2] | pm[3][lane][2];

    float sva = lscore[lane];
    float svb = hasb ? lscore[lane + 64] : 0.f;
    unsigned long long keep0 = __ballot(sva > 0.01f);
    unsigned long long keep1 = __ballot(hasb && (svb > 0.01f));
    for (int i = 0; i < TOPK; ++i) {
      bool il = i < 64;
      bool kb = il ? ((keep0 >> i) & 1ull) : ((keep1 >> (i - 64)) & 1ull);
      unsigned long long m0 = __shfl(il ? fa0 : 0ull, i & 63);
      unsigned long long m1 = __shfl(il ? fa1 : fb1, i & 63);
      if (kb) { keep0 &= ~m0; keep1 &= ~m1; }
    }
    if (lane == 0) { keepw[0] = keep0; keepw[1] = keep1; }
  }
  __syncthreads();

  // ---- outputs (threads 0..99)
  if (t < TOPK) {
    bool kp = (t < 64) ? ((keepw[0] >> t) & 1ull)
                       : ((keepw[1] >> (t - 64)) & 1ull);
    s_k[(size_t)bc * TOPK + t] = kp ? lscore[t] : 0.f;
    ((float4*)(b_k + (size_t)bc * TOPK * 4))[t] = lbox[t];
  }
}

// ---------------------------------------------------------------------------
// Kernel 4: per-image exact top-100 over 8000 candidates.
// v3: same latency treatment as kernel 2 (register-resident values, 2-replica
//     hist, mask compaction, 256-key all-thread hybrid sort).
// out layout: boxes[32][100][4] | scores[32][100] | labels[32][100] (as f32)
// ---------------------------------------------------------------------------
__global__ __launch_bounds__(256) void final_topk_kernel(
    const float* __restrict__ s_k, const float* __restrict__ b_k,
    float* __restrict__ out) {
  const int b = blockIdx.x;
  const int t = threadIdx.x;
  const int lane = t & 63;
  const int w = t >> 6;

  __shared__ __align__(16) unsigned int hist[NBIN * 2];
  __shared__ __align__(16) unsigned long long cand[NCAND];
  __shared__ int s_cnt, s_cut, wtot[4];

  const float4* src4 = (const float4*)(s_k + (size_t)b * FLATC);

  // ---- single global read: 8 float4 = 32 floats into registers
  float va[32];
#pragma unroll
  for (int i = 0; i < 8; ++i) {
    int p = t + (i << 8);
    float4 v = make_float4(0.f, 0.f, 0.f, 0.f);
    if (p < FV4) v = src4[p];
    va[4 * i + 0] = v.x; va[4 * i + 1] = v.y;
    va[4 * i + 2] = v.z; va[4 * i + 3] = v.w;
  }

  uint4* h4 = (uint4*)hist;
  const uint4 z4 = make_uint4(0u, 0u, 0u, 0u);
  h4[t] = z4;
  h4[t + 256] = z4;
  cand[t] = ~0ull;
  cand[t + 256] = ~0ull;
  if (t == 0) { s_cnt = 0; s_cut = 0; }
  __syncthreads();

#pragma unroll
  for (int j = 0; j < 32; ++j) {
    unsigned int bits = __float_as_uint(va[j]);
    if (bits != 0u) {
      int bin = (int)(bits >> 18) - BINOFF;
      bin = max(0, min(NBIN - 1, bin));
      atomicAdd(&hist[(bin << 1) | (lane & 1)], 1u);
    }
  }
  __syncthreads();

  int h[4];
  int ls;
  {
    uint4 a = h4[2 * t];
    uint4 b2 = h4[2 * t + 1];
    h[0] = (int)(a.x + a.y);
    h[1] = (int)(a.z + a.w);
    h[2] = (int)(b2.x + b2.y);
    h[3] = (int)(b2.z + b2.w);
    ls = h[0] + h[1] + h[2] + h[3];
  }
  int s = ls;
#pragma unroll
  for (int off = 1; off < 64; off <<= 1) {
    int o = __shfl_down(s, off);
    if (lane + off < 64) s += o;
  }
  if (lane == 0) wtot[w] = s;
  __syncthreads();
  int upper = 0;
  for (int w2 = w + 1; w2 < 4; ++w2) upper += wtot[w2];
  int run = (s - ls) + upper;
  int cutbin = -1;
#pragma unroll
  for (int k = 3; k >= 0; --k) {
    if (run < TOPK && run + h[k] >= TOPK) cutbin = (t << 2) + k;
    run += h[k];
  }
  if (cutbin >= 0) s_cut = cutbin;
  __syncthreads();

  const unsigned int cutbits = (unsigned int)(s_cut + BINOFF) << 18;

  unsigned int msk = 0u;
  int cnt = 0;
#pragma unroll
  for (int j = 0; j < 32; ++j) {
    unsigned int bits = __float_as_uint(va[j]);
    if (bits >= cutbits) { msk |= 1u << j; ++cnt; }
  }
  int inc = cnt;
#pragma unroll
  for (int off = 1; off < 64; off <<= 1) {
    int o = __shfl_up(inc, off);
    if (lane >= off) inc += o;
  }
  int wtotal = __shfl(inc, 63);
  int wbase = 0;
  if (lane == 63) wbase = atomicAdd(&s_cnt, wtotal);
  wbase = __shfl(wbase, 63);
  int pos = wbase + inc - cnt;
#pragma unroll
  for (int j = 0; j < 32; ++j) {
    if ((msk >> j) & 1u) {
      if (pos < NCAND) {
        unsigned int bits = __float_as_uint(va[j]);
        int idx = ((t + ((j >> 2) << 8)) << 2) + (j & 3);
        cand[pos] = (((unsigned long long)(~bits)) << 32) | (unsigned int)idx;
      }
      ++pos;
    }
  }
  __syncthreads();

  const int ncand = s_cnt;
  unsigned long long okey;
  if (ncand <= 256) {
    unsigned long long key = cand[t];
#pragma unroll
    for (int k2 = 2; k2 <= 256; k2 <<= 1) {
#pragma unroll
      for (int j = 128; j > 0; j >>= 1) {
        if (j >= k2) continue;
        const bool up = ((t & k2) == 0);
        if (j >= 64) {
          cand[t] = key;
          __syncthreads();
          unsigned long long p = cand[t ^ j];
          key = cex(key, p, up, (t & j) == 0);
          __syncthreads();
        } else {
          unsigned long long p = __shfl_xor(key, j);
          key = cex(key, p, up, (lane & j) == 0);
        }
      }
    }
    okey = key;
  } else {
    int NS = 512;
    for (int k2 = 2; k2 <= NS; k2 <<= 1) {
      for (int j = k2 >> 1; j > 0; j >>= 1) {
        if (j >= 128) {
          __syncthreads();
          for (int p = t; p < NS; p += 256) {
            int ixj = p ^ j;
            if (ixj > p) {
              unsigned long long a = cand[p], c2 = cand[ixj];
              bool up = ((p & k2) == 0);
              if (up ? (a > c2) : (a < c2)) { cand[p] = c2; cand[ixj] = a; }
            }
          }
          __syncthreads();
        } else {
          int base = w << 7;
          if (base < NS) {
#pragma unroll
            for (int half = 0; half < 2; ++half) {
              int p = base + lane + (half << 6);
              int ixj = p ^ j;
              if (ixj > p) {
                unsigned long long a = cand[p], c2 = cand[ixj];
                bool up = ((p & k2) == 0);
                if (up ? (a > c2) : (a < c2)) { cand[p] = c2; cand[ixj] = a; }
              }
            }
          }
        }
      }
    }
    __syncthreads();
    okey = cand[min(t, NCAND - 1)];
  }

  if (t < MAXDET) {
    unsigned long long key = okey;
    unsigned int vb = ~(unsigned int)(key >> 32);
    float sv = __uint_as_float(vb);
    int f = (int)(key & 0xFFFFFFFFull);
    if ((unsigned)f >= FLATC) { f = 0; sv = 0.f; }
    float4 bb = *(const float4*)(b_k + ((size_t)b * FLATC + f) * 4);
    ((float4*)out)[b * MAXDET + t] = bb;
    out[BATCH * MAXDET * 4 + b * MAXDET + t] = sv;
    int cls = f / TOPK + 1;
    out[BATCH * MAXDET * 5 + b * MAXDET + t] = (float)cls;
  }
}

// ---------------------------------------------------------------------------
extern "C" void kernel_launch(void* const* d_in, const int* in_sizes, int n_in,
                              void* d_out, int out_size, void* d_ws,
                              size_t ws_size, hipStream_t stream) {
  const float* cls_logits = (const float*)d_in[0];
  const float* bbox_pred  = (const float*)d_in[1];
  const float* priors     = (const float*)d_in[2];
  float* out = (float*)d_out;

  float* scores_t = (float*)d_ws;                                  // [B][NT][80][64]
  float* s_k = scores_t + (size_t)BATCH * NT * NC1 * 64;           // [2560][100]
  float* b_k = s_k + (size_t)BATCH * NC1 * TOPK;                   // [2560][100][4]
  unsigned long long* k_sel =
      (unsigned long long*)(b_k + (size_t)BATCH * NC1 * TOPK * 4); // [2560][100]

  softmax_transpose_kernel<<<BATCH * NT, 256, 0, stream>>>(cls_logits,
                                                           scores_t);
  topk_select_kernel<<<BATCH * NC1, 256, 0, stream>>>(scores_t, k_sel);
  nms_kernel<<<BATCH * NC1, 256, 0, stream>>>(k_sel, bbox_pred, priors,
                                              s_k, b_k);
  final_topk_kernel<<<BATCH, 256, 0, stream>>>(s_k, b_k, out);
}